// Round 6
// baseline (489.955 us; speedup 1.0000x reference)
//
#include <hip/hip_runtime.h>

constexpr int C  = 256;
constexpr int H  = 224;
constexpr int W  = 224;
constexpr int HW = H * W;               // 50176
constexpr int PIX = 64;                 // pixels per block (16 per wave)
constexpr int THREADS = 256;
constexpr int TILES_PER_B = HW / PIX;   // 784 (exact)
constexpr int BATCH = 16;

typedef float f32x4 __attribute__((ext_vector_type(4)));

__global__ __launch_bounds__(THREADS, 4)
void fused_sigmoid_border_scale(const float* __restrict__ x,
                                const float* __restrict__ wv,
                                const float* __restrict__ bv,
                                float* __restrict__ out)
{
    const int t    = threadIdx.x;
    const int wave = t >> 6;
    const int lane = t & 63;
    const int q    = lane & 3;    // pixel column: px q*4..q*4+3 of this wave's 16
    const int cg   = lane >> 2;   // channel subgroup 0..15

    const int blk  = blockIdx.x;
    const int b    = blk / TILES_PER_B;
    const int hw0  = (blk - b * TILES_PER_B) * PIX;
    const int px   = hw0 + wave * 16 + q * 4;   // this lane's 4 pixels

    const float* xb = x   + (size_t)b * C * HW + px;
    float*       ob = out + (size_t)b * C * HW + px;

    // ---- load 16 channels x 4 pixels into registers (16B per lane) ----
    f32x4 v[16];
    #pragma unroll
    for (int k = 0; k < 16; ++k) {
        const int c = k * 16 + cg;
        v[k] = __builtin_nontemporal_load(
            reinterpret_cast<const f32x4*>(xb + (size_t)c * HW));
    }

    // this lane's 16 channel weights
    const float b0 = bv[0];
    float wk[16];
    #pragma unroll
    for (int k = 0; k < 16; ++k) wk[k] = wv[k * 16 + cg];

    // ---- per-lane partial dot over its 16 channels ----
    f32x4 acc = (f32x4)(0.f);
    #pragma unroll
    for (int k = 0; k < 16; ++k) {
        acc.x = fmaf(v[k].x, wk[k], acc.x);
        acc.y = fmaf(v[k].y, wk[k], acc.y);
        acc.z = fmaf(v[k].z, wk[k], acc.z);
        acc.w = fmaf(v[k].w, wk[k], acc.w);
    }

    // keep the tile live in VGPRs — forbid load rematerialization
    #pragma unroll
    for (int k = 0; k < 16; ++k)
        asm volatile("" : "+v"(v[k]));

    // ---- full intra-wave reduce across 16 cg-subgroups (lane bits 2..5) ----
    #pragma unroll
    for (int m = 4; m <= 32; m <<= 1) {
        acc.x += __shfl_xor(acc.x, m);
        acc.y += __shfl_xor(acc.y, m);
        acc.z += __shfl_xor(acc.z, m);
        acc.w += __shfl_xor(acc.w, m);
    }

    // ---- sigmoid + border for this lane's 4 pixels (no barrier, no LDS) ----
    f32x4 comb;
    #pragma unroll
    for (int j = 0; j < 4; ++j) {
        const float att = 1.0f / (1.0f + expf(-(acc[j] + b0)));
        const int hw = px + j;
        const int h  = hw / W;
        const int w  = hw - h * W;
        const bool border = (h == 0) | (h == H - 1) | (w == 0) | (w == W - 1);
        comb[j] = att * (border ? 2.0f : 1.0f);
    }

    // ---- scale and store (16B per lane) ----
    #pragma unroll
    for (int k = 0; k < 16; ++k) {
        const int c = k * 16 + cg;
        __builtin_nontemporal_store(v[k] * comb,
            reinterpret_cast<f32x4*>(ob + (size_t)c * HW));
    }
}

extern "C" void kernel_launch(void* const* d_in, const int* in_sizes, int n_in,
                              void* d_out, int out_size, void* d_ws, size_t ws_size,
                              hipStream_t stream) {
    const float* x  = (const float*)d_in[0];
    const float* wv = (const float*)d_in[1];
    const float* bv = (const float*)d_in[2];
    float* out = (float*)d_out;

    dim3 grid(BATCH * TILES_PER_B);   // 12544 blocks, one 64-pixel tile each
    fused_sigmoid_border_scale<<<grid, THREADS, 0, stream>>>(x, wv, bv, out);
}

// Round 7
// 408.828 us; speedup vs baseline: 1.1984x; 1.1984x over previous
//
#include <hip/hip_runtime.h>

constexpr int C  = 256;
constexpr int H  = 224;
constexpr int W  = 224;
constexpr int HW = H * W;               // 50176
constexpr int PIX = 64;                 // pixels per block
constexpr int THREADS = 512;
constexpr int TILES_PER_B = HW / PIX;   // 784 (exact)
constexpr int BATCH = 16;

typedef float f32x4 __attribute__((ext_vector_type(4)));

__global__ __launch_bounds__(THREADS, 8)
void fused_sigmoid_border_scale(const float* __restrict__ x,
                                const float* __restrict__ wv,
                                const float* __restrict__ bv,
                                float* __restrict__ out)
{
    __shared__ f32x4 pw[8][16];    // [wave][q] partial sums, 2 KB

    const int t    = threadIdx.x;
    const int q    = t & 15;       // float4 column (pixels q*4..q*4+3)
    const int c0   = t >> 4;       // channel subgroup 0..31 (wave w covers 4w..4w+3)
    const int wave = t >> 6;
    const int blk  = blockIdx.x;
    const int b    = blk / TILES_PER_B;
    const int hw0  = (blk - b * TILES_PER_B) * PIX;

    const float* xbase = x   + (size_t)b * (C * HW);   // SGPR base
    float*       obase = out + (size_t)b * (C * HW);   // SGPR base
    const uint32_t pixoff = (uint32_t)(hw0 + q * 4);

    // ---- load 8 channels x 4 pixels into registers (4x256B segments per wave-instr) ----
    f32x4 v[8];
    uint32_t off[8];
    #pragma unroll
    for (int k = 0; k < 8; ++k) {
        off[k] = (uint32_t)((k * 32 + c0) * HW) + pixoff;
        v[k] = __builtin_nontemporal_load(
            reinterpret_cast<const f32x4*>(xbase + off[k]));
    }

    // ---- per-thread partial dot over its 8 channels ----
    f32x4 acc = (f32x4)(0.f);
    #pragma unroll
    for (int k = 0; k < 8; ++k) {
        const float wk = wv[k * 32 + c0];
        acc.x = fmaf(v[k].x, wk, acc.x);
        acc.y = fmaf(v[k].y, wk, acc.y);
        acc.z = fmaf(v[k].z, wk, acc.z);
        acc.w = fmaf(v[k].w, wk, acc.w);
    }

    // keep the tile live in VGPRs — forbid load rematerialization
    #pragma unroll
    for (int k = 0; k < 8; ++k)
        asm volatile("" : "+v"(v[k]));

    // ---- intra-wave reduce across this wave's 4 c0-subgroups (lane bits 4,5) ----
    #pragma unroll
    for (int m = 16; m <= 32; m <<= 1) {
        acc.x += __shfl_xor(acc.x, m);
        acc.y += __shfl_xor(acc.y, m);
        acc.z += __shfl_xor(acc.z, m);
        acc.w += __shfl_xor(acc.w, m);
    }
    if ((t & 63) < 16) pw[wave][q] = acc;   // one f32x4 per q per wave
    __syncthreads();                        // the ONLY barrier

    // ---- every thread: combine 8 wave-partials + sigmoid + border for its 4 px ----
    const f32x4 s4 = ((pw[0][q] + pw[1][q]) + (pw[2][q] + pw[3][q]))
                   + ((pw[4][q] + pw[5][q]) + (pw[6][q] + pw[7][q]));
    const float b0 = bv[0];
    f32x4 comb;
    #pragma unroll
    for (int j = 0; j < 4; ++j) {
        const float att = 1.0f / (1.0f + expf(-(s4[j] + b0)));
        const int hw = hw0 + q * 4 + j;
        const int h  = hw / W;
        const int w  = hw - h * W;
        const bool border = (h == 0) | (h == H - 1) | (w == 0) | (w == W - 1);
        comb[j] = att * (border ? 2.0f : 1.0f);
    }

    // ---- scale registers and store (same offsets, other base) ----
    #pragma unroll
    for (int k = 0; k < 8; ++k) {
        __builtin_nontemporal_store(v[k] * comb,
            reinterpret_cast<f32x4*>(obase + off[k]));
    }
}

extern "C" void kernel_launch(void* const* d_in, const int* in_sizes, int n_in,
                              void* d_out, int out_size, void* d_ws, size_t ws_size,
                              hipStream_t stream) {
    const float* x  = (const float*)d_in[0];
    const float* wv = (const float*)d_in[1];
    const float* bv = (const float*)d_in[2];
    float* out = (float*)d_out;

    dim3 grid(BATCH * TILES_PER_B);   // 12544 blocks, one 64-pixel tile each
    fused_sigmoid_border_scale<<<grid, THREADS, 0, stream>>>(x, wv, bv, out);
}

// Round 8
// 357.281 us; speedup vs baseline: 1.3713x; 1.1443x over previous
//
#include <hip/hip_runtime.h>

constexpr int C  = 256;
constexpr int H  = 224;
constexpr int W  = 224;
constexpr int HW = H * W;               // 50176
constexpr int PIX = 64;                 // pixels per block
constexpr int THREADS = 256;
constexpr int TILES_PER_B = HW / PIX;   // 784 (exact)
constexpr int BATCH = 16;

typedef float f32x4 __attribute__((ext_vector_type(4)));

__global__ __launch_bounds__(THREADS, 8)
void fused_sigmoid_border_scale(const float* __restrict__ x,
                                const float* __restrict__ wv,
                                const float* __restrict__ bv,
                                float* __restrict__ out)
{
    __shared__ f32x4 pw[4][16];    // [wave][q] partial sums, 1 KB

    const int t    = threadIdx.x;
    const int q    = t & 15;       // float4 column (pixels q*4..q*4+3)
    const int c0   = t >> 4;       // channel subgroup 0..15
    const int wave = t >> 6;
    const int blk  = blockIdx.x;
    const int b    = blk / TILES_PER_B;
    const int hw0  = (blk - b * TILES_PER_B) * PIX;

    const float* xb = x   + (size_t)b * C * HW + hw0 + q * 4;
    float*       ob = out + (size_t)b * C * HW + hw0 + q * 4;

    // ---- pass 1: dot-product; loads populate L2/L3 and are DISCARDED ----
    f32x4 acc = (f32x4)(0.f);
    #pragma unroll
    for (int k = 0; k < 16; ++k) {
        const int c = k * 16 + c0;
        const f32x4 v = *reinterpret_cast<const f32x4*>(xb + (size_t)c * HW);
        const float wk = wv[c];
        acc.x = fmaf(v.x, wk, acc.x);
        acc.y = fmaf(v.y, wk, acc.y);
        acc.z = fmaf(v.z, wk, acc.z);
        acc.w = fmaf(v.w, wk, acc.w);
    }

    // ---- intra-wave reduce across this wave's 4 c0-subgroups (lane bits 4,5) ----
    #pragma unroll
    for (int m = 16; m <= 32; m <<= 1) {
        acc.x += __shfl_xor(acc.x, m);
        acc.y += __shfl_xor(acc.y, m);
        acc.z += __shfl_xor(acc.z, m);
        acc.w += __shfl_xor(acc.w, m);
    }
    if ((t & 63) < 16) pw[wave][q] = acc;   // one f32x4 per q per wave
    __syncthreads();                        // the ONLY barrier

    // ---- every thread: combine 4 wave-partials + sigmoid + border ----
    const f32x4 s4 = (pw[0][q] + pw[1][q]) + (pw[2][q] + pw[3][q]);
    const float b0 = bv[0];
    f32x4 comb;
    #pragma unroll
    for (int j = 0; j < 4; ++j) {
        const float att = 1.0f / (1.0f + expf(-(s4[j] + b0)));
        const int hw = hw0 + q * 4 + j;
        const int h  = hw / W;
        const int w  = hw - h * W;
        const bool border = (h == 0) | (h == H - 1) | (w == 0) | (w == W - 1);
        comb[j] = att * (border ? 2.0f : 1.0f);
    }

    // ---- pass 2: re-read (L3-hot), scale, NT store ----
    #pragma unroll
    for (int k = 0; k < 16; ++k) {
        const int c = k * 16 + c0;
        const f32x4 v = *reinterpret_cast<const f32x4*>(xb + (size_t)c * HW);
        __builtin_nontemporal_store(v * comb,
            reinterpret_cast<f32x4*>(ob + (size_t)c * HW));
    }
}

extern "C" void kernel_launch(void* const* d_in, const int* in_sizes, int n_in,
                              void* d_out, int out_size, void* d_ws, size_t ws_size,
                              hipStream_t stream) {
    const float* x  = (const float*)d_in[0];
    const float* wv = (const float*)d_in[1];
    const float* bv = (const float*)d_in[2];
    float* out = (float*)d_out;

    dim3 grid(BATCH * TILES_PER_B);   // 12544 blocks, one 64-pixel tile each
    fused_sigmoid_border_scale<<<grid, THREADS, 0, stream>>>(x, wv, bv, out);
}

// Round 9
// 304.090 us; speedup vs baseline: 1.6112x; 1.1749x over previous
//
#include <hip/hip_runtime.h>

constexpr int C  = 256;
constexpr int H  = 224;
constexpr int W  = 224;
constexpr int HW = H * W;               // 50176
constexpr int PIX = 128;                // pixels per block (32 float4 columns)
constexpr int THREADS = 512;
constexpr int TILES_PER_B = HW / PIX;   // 392 (exact)
constexpr int BATCH = 16;

typedef float f32x4 __attribute__((ext_vector_type(4)));

__global__ __launch_bounds__(THREADS, 4)
void fused_sigmoid_border_scale(const float* __restrict__ x,
                                const float* __restrict__ wv,
                                const float* __restrict__ bv,
                                float* __restrict__ out)
{
    __shared__ f32x4 pw[8][32];    // [wave][col] partial sums, 4 KB

    const int t    = threadIdx.x;
    const int q    = t & 31;       // float4 column (pixels q*4..q*4+3)
    const int c0   = t >> 5;       // channel subgroup 0..15 (wave w covers 2w,2w+1)
    const int wave = t >> 6;
    const int blk  = blockIdx.x;
    const int b    = blk / TILES_PER_B;
    const int hw0  = (blk - b * TILES_PER_B) * PIX;

    const float* xb = x   + (size_t)b * C * HW + hw0 + q * 4;
    float*       ob = out + (size_t)b * C * HW + hw0 + q * 4;

    // ---- load 16 channels x 4 pixels into registers (2x512B segments/instr) ----
    f32x4 v[16];
    #pragma unroll
    for (int k = 0; k < 16; ++k) {
        const int c = k * 16 + c0;
        v[k] = __builtin_nontemporal_load(
            reinterpret_cast<const f32x4*>(xb + (size_t)c * HW));
    }

    // ---- per-thread partial dot over its 16 channels ----
    f32x4 acc = (f32x4)(0.f);
    #pragma unroll
    for (int k = 0; k < 16; ++k) {
        const float wk = wv[k * 16 + c0];
        acc.x = fmaf(v[k].x, wk, acc.x);
        acc.y = fmaf(v[k].y, wk, acc.y);
        acc.z = fmaf(v[k].z, wk, acc.z);
        acc.w = fmaf(v[k].w, wk, acc.w);
    }

    // keep the tile live in VGPRs — forbid load rematerialization
    #pragma unroll
    for (int k = 0; k < 16; ++k)
        asm volatile("" : "+v"(v[k]));

    // ---- fold the wave's two c0-subgroups (lane bit 5) ----
    acc.x += __shfl_xor(acc.x, 32);
    acc.y += __shfl_xor(acc.y, 32);
    acc.z += __shfl_xor(acc.z, 32);
    acc.w += __shfl_xor(acc.w, 32);
    if ((t & 63) < 32) pw[wave][q] = acc;   // one f32x4 per col per wave
    __syncthreads();                        // the ONLY barrier

    // ---- every thread: combine 8 wave-partials + sigmoid + border ----
    const f32x4 s4 = ((pw[0][q] + pw[1][q]) + (pw[2][q] + pw[3][q]))
                   + ((pw[4][q] + pw[5][q]) + (pw[6][q] + pw[7][q]));
    const float b0 = bv[0];
    f32x4 comb;
    #pragma unroll
    for (int j = 0; j < 4; ++j) {
        const float att = 1.0f / (1.0f + expf(-(s4[j] + b0)));
        const int hw = hw0 + q * 4 + j;
        const int h  = hw / W;
        const int w  = hw - h * W;
        const bool border = (h == 0) | (h == H - 1) | (w == 0) | (w == W - 1);
        comb[j] = att * (border ? 2.0f : 1.0f);
    }

    // ---- scale registers and store (2x512B segments/instr) ----
    #pragma unroll
    for (int k = 0; k < 16; ++k) {
        const int c = k * 16 + c0;
        __builtin_nontemporal_store(v[k] * comb,
            reinterpret_cast<f32x4*>(ob + (size_t)c * HW));
    }
}

extern "C" void kernel_launch(void* const* d_in, const int* in_sizes, int n_in,
                              void* d_out, int out_size, void* d_ws, size_t ws_size,
                              hipStream_t stream) {
    const float* x  = (const float*)d_in[0];
    const float* wv = (const float*)d_in[1];
    const float* bv = (const float*)d_in[2];
    float* out = (float*)d_out;

    dim3 grid(BATCH * TILES_PER_B);   // 6272 blocks, one 128-pixel tile each
    fused_sigmoid_border_scale<<<grid, THREADS, 0, stream>>>(x, wv, bv, out);
}